// Round 13
// baseline (1071.824 us; speedup 1.0000x reference)
//
#include <hip/hip_runtime.h>
#include <math.h>

#define LCNT 4

typedef float f32x4 __attribute__((ext_vector_type(4)));
typedef short bf16x8 __attribute__((ext_vector_type(8)));
typedef unsigned int u32;

__device__ __forceinline__ ushort bfr(float x){
  unsigned int b = __float_as_uint(x);
  return (ushort)((b + 0x7FFFu + ((b>>16)&1u)) >> 16);
}
__device__ __forceinline__ unsigned int pk2(float a, float b){
  return (unsigned int)bfr(a) | ((unsigned int)bfr(b)<<16);
}
__device__ __forceinline__ float bflo(u32 u){ return __uint_as_float(u<<16); }
__device__ __forceinline__ float bfhi(u32 u){ return __uint_as_float(u & 0xffff0000u); }
__device__ __forceinline__ float fast_gelu(float v){
  float v2 = v*v;
  float u = v*(-1.5957691f - 0.0713548162f*v2);
  float e = __expf(u);
  return v*__builtin_amdgcn_rcpf(1.f + e);
}
__device__ __forceinline__ void gl_lds16(const void* g, void* l){
  __builtin_amdgcn_global_load_lds(
      (const __attribute__((address_space(1))) u32*)g,
      (__attribute__((address_space(3))) u32*)l, 16, 0, 0);
}

// ---------------- transpose x[B,D,L,N] -> y[B,L,N,D] ----------------
__global__ __launch_bounds__(256) void k_transpose(const float* __restrict__ x,
                                                   float* __restrict__ y){
  int g = blockIdx.x;            // b*1024 + l
  int b = g >> 10, l = g & 1023;
  __shared__ float sh[128*65];
  for (int idx = threadIdx.x; idx < 128*64; idx += 256){
    int d = idx >> 6, n = idx & 63;
    sh[d*65+n] = x[(((size_t)b*128 + d)*1024 + l)*64 + n];
  }
  __syncthreads();
  for (int idx = threadIdx.x; idx < 128*64; idx += 256){
    int n = idx >> 7, d = idx & 127;
    y[((size_t)g*64 + n)*128 + d] = sh[d*65+n];
  }
}

// ---------------- fp32 -> bf16 weight conversion ----------------
__global__ __launch_bounds__(256) void k_cvt(const float* __restrict__ src,
                                             ushort* __restrict__ dst, int n4){
  int i = blockIdx.x*256 + threadIdx.x;
  if (i < n4){
    float4 v = ((const float4*)src)[i];
    ushort4 p; p.x=bfr(v.x); p.y=bfr(v.y); p.z=bfr(v.z); p.w=bfr(v.w);
    ((ushort4*)dst)[i] = p;
  }
}

// ---------------- standalone k_row (layer 0 only) — round-12 verified ----
#define HSTRB 136   // ushort stride (rows 16B-aligned)
__global__ __launch_bounds__(256) void k_row(
    float* __restrict__ y,
    const float* __restrict__ rqw, const float* __restrict__ rqb,
    const float* __restrict__ rkw, const float* __restrict__ rkb,
    const float* __restrict__ rvw, const float* __restrict__ rvb,
    const float* __restrict__ roW, const float* __restrict__ rob,
    const float* __restrict__ lrg, const float* __restrict__ lrb,
    const float* __restrict__ cqw, const float* __restrict__ cqb,
    const float* __restrict__ ckw, const float* __restrict__ ckb,
    const float* __restrict__ lcg, const float* __restrict__ lcb,
    float2* __restrict__ stats,
    float* __restrict__ qout, float* __restrict__ kout)
{
  int g = blockIdx.x;
  __shared__ __align__(16) ushort sh_h[64*HSTRB];
  __shared__ __align__(16) float sh_w4[2048];
  __shared__ float sh_q[256], sh_k[256];
  __shared__ __align__(16) float sh_hkP[512];
  __shared__ __align__(16) float sh_ktv[128];
  int tid = threadIdx.x;
  int wid = tid>>6, ln = tid&63;
  {
    const float* wsrc = (wid==0)?rqw:(wid==1)?rkw:(wid==2)?cqw:ckw;
    gl_lds16(wsrc + ln*4,       &sh_w4[wid*512]);
    gl_lds16(wsrc + 256 + ln*4, &sh_w4[wid*512 + 256]);
  }
  int ttk = tid>>2, s4 = tid&3;
  float* yr = y + ((size_t)g*64 + ttk)*128 + s4*32;
  float4 v[8];
  #pragma unroll
  for (int i=0;i<8;i++) v[i] = *(const float4*)(yr + i*4);
  float sum = 0.f;
  #pragma unroll
  for (int i=0;i<8;i++) sum += v[i].x+v[i].y+v[i].z+v[i].w;
  sum += __shfl_xor(sum,1); sum += __shfl_xor(sum,2);
  float mean = sum*(1.0f/128.0f);
  float vs = 0.f;
  #pragma unroll
  for (int i=0;i<8;i++){
    v[i].x-=mean; v[i].y-=mean; v[i].z-=mean; v[i].w-=mean;
    vs += v[i].x*v[i].x+v[i].y*v[i].y+v[i].z*v[i].z+v[i].w*v[i].w;
  }
  vs += __shfl_xor(vs,1); vs += __shfl_xor(vs,2);
  float rstd = rsqrtf(vs*(1.0f/128.0f) + 1e-5f);
  {
    const float* gp = lrg + s4*32; const float* bp = lrb + s4*32;
    ushort* hrow = &sh_h[ttk*HSTRB + s4*32];
    #pragma unroll
    for (int i=0;i<8;i++){
      float4 g4 = *(const float4*)(gp+i*4);
      float4 b4 = *(const float4*)(bp+i*4);
      uint2 o2;
      o2.x = pk2(v[i].x*rstd*g4.x+b4.x, v[i].y*rstd*g4.y+b4.y);
      o2.y = pk2(v[i].z*rstd*g4.z+b4.z, v[i].w*rstd*g4.w+b4.w);
      *(uint2*)&hrow[i*4] = o2;
    }
  }
  __syncthreads();
  int h = tid>>6, n = tid&63;
  {
    float qr = rqb[h], kr = rkb[h];
    const int4* hp = (const int4*)&sh_h[n*HSTRB];
    const float4* qwp = (const float4*)&sh_w4[h*128];
    const float4* kwp = (const float4*)&sh_w4[512 + h*128];
    #pragma unroll 4
    for (int j=0;j<16;j++){
      int4 h8 = hp[j];
      float4 qa = qwp[2*j], qb4 = qwp[2*j+1];
      float4 ka = kwp[2*j], kb4 = kwp[2*j+1];
      float h0=bflo((u32)h8.x), h1=bfhi((u32)h8.x);
      float h2=bflo((u32)h8.y), h3=bfhi((u32)h8.y);
      float h4=bflo((u32)h8.z), h5=bfhi((u32)h8.z);
      float h6=bflo((u32)h8.w), h7=bfhi((u32)h8.w);
      qr += h0*qa.x+h1*qa.y+h2*qa.z+h3*qa.w + h4*qb4.x+h5*qb4.y+h6*qb4.z+h7*qb4.w;
      kr += h0*ka.x+h1*ka.y+h2*ka.z+h3*ka.w + h4*kb4.x+h5*kb4.y+h6*kb4.z+h7*kb4.w;
    }
    qr = qr > 0.f ? qr + 1.f : __expf(qr);
    kr = kr > 0.f ? kr + 1.f : __expf(kr);
    float qs = qr; for (int m=32;m>=1;m>>=1) qs += __shfl_xor(qs, m);
    float ks = kr; for (int m=32;m>=1;m>>=1) ks += __shfl_xor(ks, m);
    sh_q[h*64+n] = qr * (64.f/qs);
    sh_k[h*64+n] = kr * (1.f/ks);
  }
  __syncthreads();
  #pragma unroll
  for (int r=0;r<2;r++){
    int idx = tid + r*256;
    int hh = idx>>7, d = idx&127;
    float acc = 0.f;
    #pragma unroll 4
    for (int nn=0;nn<64;nn++)
      acc += sh_k[hh*64+nn]*bflo((u32)sh_h[nn*HSTRB+d]);
    sh_hkP[hh*128+d] = acc;
  }
  __syncthreads();
  if (tid < 128){
    float acc = rvb[tid];
    const float4* vr = (const float4*)(rvw + (size_t)tid*128);
    const float4* hp2 = (const float4*)(sh_hkP + (tid>>5)*128);
    #pragma unroll 8
    for (int j=0;j<32;j++){
      float4 a = vr[j], bq = hp2[j];
      acc += a.x*bq.x + a.y*bq.y + a.z*bq.z + a.w*bq.w;
    }
    sh_ktv[tid] = acc;
  }
  __syncthreads();
  #pragma unroll
  for (int r=0;r<2;r++){
    int idx = tid + r*256;
    int hh = idx>>7, e = idx&127;
    float acc = 0.f;
    const float4* orow = (const float4*)(roW + (size_t)e*128 + hh*32);
    const float4* kt = (const float4*)(sh_ktv + hh*32);
    #pragma unroll
    for (int j=0;j<8;j++){
      float4 a = orow[j], bq = kt[j];
      acc += a.x*bq.x + a.y*bq.y + a.z*bq.z + a.w*bq.w;
    }
    sh_hkP[hh*128+e] = acc;
  }
  __syncthreads();
  {
    float q0=sh_q[ttk], q1=sh_q[64+ttk], q2=sh_q[128+ttk], q3=sh_q[192+ttk];
    const float4* P4 = (const float4*)sh_hkP;
    #pragma unroll
    for (int i=0;i<8;i++){
      int d4 = s4*8 + i;
      float4 p0=P4[d4], p1=P4[32+d4], p2=P4[64+d4], p3=P4[96+d4];
      float4 o4=*(const float4*)&rob[s4*32+i*4];
      v[i].x += mean + o4.x + q0*p0.x+q1*p1.x+q2*p2.x+q3*p3.x;
      v[i].y += mean + o4.y + q0*p0.y+q1*p1.y+q2*p2.y+q3*p3.y;
      v[i].z += mean + o4.z + q0*p0.z+q1*p1.z+q2*p2.z+q3*p3.z;
      v[i].w += mean + o4.w + q0*p0.w+q1*p1.w+q2*p2.w+q3*p3.w;
      *(float4*)(yr + i*4) = v[i];
    }
  }
  float sum2 = 0.f;
  #pragma unroll
  for (int i=0;i<8;i++) sum2 += v[i].x+v[i].y+v[i].z+v[i].w;
  sum2 += __shfl_xor(sum2,1); sum2 += __shfl_xor(sum2,2);
  float cmean = sum2*(1.0f/128.0f);
  float cvs = 0.f;
  #pragma unroll
  for (int i=0;i<8;i++){
    v[i].x-=cmean; v[i].y-=cmean; v[i].z-=cmean; v[i].w-=cmean;
    cvs += v[i].x*v[i].x+v[i].y*v[i].y+v[i].z*v[i].z+v[i].w*v[i].w;
  }
  cvs += __shfl_xor(cvs,1); cvs += __shfl_xor(cvs,2);
  float crstd = rsqrtf(cvs*(1.0f/128.0f) + 1e-5f);
  if (s4 == 0) stats[(size_t)g*64 + ttk] = make_float2(cmean, crstd);
  {
    const float* gp = lcg + s4*32; const float* bp = lcb + s4*32;
    ushort* hrow = &sh_h[ttk*HSTRB + s4*32];
    #pragma unroll
    for (int i=0;i<8;i++){
      float4 g4 = *(const float4*)(gp+i*4);
      float4 b4 = *(const float4*)(bp+i*4);
      uint2 o2;
      o2.x = pk2(v[i].x*crstd*g4.x+b4.x, v[i].y*crstd*g4.y+b4.y);
      o2.y = pk2(v[i].z*crstd*g4.z+b4.z, v[i].w*crstd*g4.w+b4.w);
      *(uint2*)&hrow[i*4] = o2;
    }
  }
  __syncthreads();
  {
    float qv = cqb[h], kv = ckb[h];
    const int4* hp = (const int4*)&sh_h[n*HSTRB];
    const float4* qwp = (const float4*)&sh_w4[1024 + h*128];
    const float4* kwp = (const float4*)&sh_w4[1536 + h*128];
    #pragma unroll 4
    for (int j=0;j<16;j++){
      int4 h8 = hp[j];
      float4 qa = qwp[2*j], qb4 = qwp[2*j+1];
      float4 ka = kwp[2*j], kb4 = kwp[2*j+1];
      float h0=bflo((u32)h8.x), h1=bfhi((u32)h8.x);
      float h2=bflo((u32)h8.y), h3=bfhi((u32)h8.y);
      float h4=bflo((u32)h8.z), h5=bfhi((u32)h8.z);
      float h6=bflo((u32)h8.w), h7=bfhi((u32)h8.w);
      qv += h0*qa.x+h1*qa.y+h2*qa.z+h3*qa.w + h4*qb4.x+h5*qb4.y+h6*qb4.z+h7*qb4.w;
      kv += h0*ka.x+h1*ka.y+h2*ka.z+h3*ka.w + h4*kb4.x+h5*kb4.y+h6*kb4.z+h7*kb4.w;
    }
    qv = qv > 0.f ? qv + 1.f : __expf(qv);
    kv = kv > 0.f ? kv + 1.f : __expf(kv);
    size_t o = (size_t)g*256 + tid;
    qout[o] = qv; kout[o] = kv;
  }
}

// ---------------- col: q-sum partials over l chunks ----------------
__global__ __launch_bounds__(256) void k_qsum(const float* __restrict__ qin,
                                              float* __restrict__ qsp){
  int gg = blockIdx.x;  // b*8 + c
  int c = gg&7, b = gg>>3;
  int tid = threadIdx.x;
  const float* qp = qin + ((size_t)b*1024 + c*128)*256 + tid;
  float s = 0.f;
  #pragma unroll 4
  for (int j=0;j<128;j++){ s += *qp; qp += 256; }
  qsp[(size_t)gg*256 + tid] = s;       // [b][c][h*64+n]
}

// ---------------- col: streaming reduce S1[d]=Σk·r·y, A=Σk, B=Σk·r·m ----
__global__ __launch_bounds__(256) void k_col_s1(
    const float* __restrict__ y, const float2* __restrict__ stats,
    const float* __restrict__ kin,
    float* __restrict__ s1p, float* __restrict__ Ab, float* __restrict__ Bb)
{
  int gg = blockIdx.x;                   // ((b*64+n)*8+s)
  int s = gg & 7, n = (gg>>3) & 63, b = gg>>9;
  int tid = threadIdx.x;
  int li = tid>>7, d = tid&127;
  const float* kp = kin + (size_t)b*262144 + n;   // [b][l][h][n]
  float a0=0.f,a1=0.f,a2=0.f,a3=0.f;
  float A0=0.f,A1=0.f,A2=0.f,A3=0.f;
  float B0=0.f,B1=0.f,B2=0.f,B3=0.f;
  for (int j=0;j<64;j++){
    int l = s*128 + 2*j + li;
    size_t t = ((size_t)(b*1024+l)*64+n);
    float2 st = stats[t];
    float w = st.y * y[t*128 + d];
    float rm = st.y*st.x;
    const float* kl = kp + (size_t)l*256;
    float k0 = kl[0], k1 = kl[64], k2 = kl[128], k3 = kl[192];
    a0 += k0*w; a1 += k1*w; a2 += k2*w; a3 += k3*w;
    A0 += k0; A1 += k1; A2 += k2; A3 += k3;
    B0 += k0*rm; B1 += k1*rm; B2 += k2*rm; B3 += k3*rm;
  }
  __shared__ float shr[512];
  __shared__ float sAB[8];
  if (li == 1){
    shr[0*128+d]=a0; shr[1*128+d]=a1; shr[2*128+d]=a2; shr[3*128+d]=a3;
    if (d==0){ sAB[0]=A0; sAB[1]=A1; sAB[2]=A2; sAB[3]=A3;
               sAB[4]=B0; sAB[5]=B1; sAB[6]=B2; sAB[7]=B3; }
  }
  __syncthreads();
  if (li == 0){
    float* out = s1p + (size_t)gg*512;
    out[0*128+d] = a0 + shr[0*128+d];
    out[1*128+d] = a1 + shr[1*128+d];
    out[2*128+d] = a2 + shr[2*128+d];
    out[3*128+d] = a3 + shr[3*128+d];
    if (d==0){
      Ab[gg*4+0]=A0+sAB[0]; Ab[gg*4+1]=A1+sAB[1];
      Ab[gg*4+2]=A2+sAB[2]; Ab[gg*4+3]=A3+sAB[3];
      Bb[gg*4+0]=B0+sAB[4]; Bb[gg*4+1]=B1+sAB[5];
      Bb[gg*4+2]=B2+sAB[6]; Bb[gg*4+3]=B3+sAB[7];
    }
  }
}

// ---------------- col: reduce S1/A/B/qs -> hk -> ktv -> P ----------------
__global__ __launch_bounds__(256) void k_col_ktvP(
    const float* __restrict__ s1p,
    const float* __restrict__ Ab, const float* __restrict__ Bb,
    const float* __restrict__ qsp,
    const float* __restrict__ vw, const float* __restrict__ vb,
    const float* __restrict__ ow,
    const float* __restrict__ lcg, const float* __restrict__ lcb,
    float* __restrict__ Pout)
{
  int gg = blockIdx.x;   // b*64+n
  int b = gg>>6, n = gg&63;
  __shared__ float sh_hk[512];
  __shared__ float sh_ktv[128];
  __shared__ float sh_A[4], sh_B[4], sh_qs[4];
  int tid = threadIdx.x;
  #pragma unroll
  for (int r = 0; r < 2; r++){
    int idx = tid + r*256;
    float acc = 0.f;
    #pragma unroll
    for (int s = 0; s < 8; s++) acc += s1p[((size_t)gg*8 + s)*512 + idx];
    sh_hk[idx] = acc;
  }
  if (tid < 4){
    float a=0.f, bb=0.f, q=0.f;
    #pragma unroll
    for (int s = 0; s < 8; s++){ a += Ab[(gg*8+s)*4+tid]; bb += Bb[(gg*8+s)*4+tid]; }
    #pragma unroll
    for (int c = 0; c < 8; c++) q += qsp[((b*8+c)<<8) + (tid<<6) + n];
    sh_A[tid]=a; sh_B[tid]=bb; sh_qs[tid] = 1024.f/q;
  }
  __syncthreads();
  #pragma unroll
  for (int r = 0; r < 2; r++){
    int idx = tid + r*256;
    int h = idx>>7, d = idx&127;
    sh_hk[idx] = lcg[d]*((sh_hk[idx]-sh_B[h])/sh_A[h]) + lcb[d];
  }
  __syncthreads();
  if (tid < 128){
    float acc = vb[tid];
    const float* vr = vw + (size_t)tid*128;
    const float* hp2 = sh_hk + (tid>>5)*128;
    #pragma unroll 4
    for (int d = 0; d < 128; d++) acc += vr[d]*hp2[d];
    sh_ktv[tid] = acc;
  }
  __syncthreads();
  #pragma unroll
  for (int r = 0; r < 2; r++){
    int idx = tid + r*256;
    int hh = idx >> 7, e = idx & 127;
    float acc = 0.f;
    const float* orow = ow + (size_t)e*128 + hh*32;
    #pragma unroll 4
    for (int j = 0; j < 32; j++) acc += orow[j]*sh_ktv[hh*32+j];
    Pout[(size_t)gg*512 + hh*128 + e] = acc * sh_qs[hh];
  }
}

// ---------------- standalone k_ffn (layer 3 tail) — round-12 verified ----
__global__ __launch_bounds__(512, 2) void k_ffn(
    float* __restrict__ y,
    const float* __restrict__ qbuf, const float* __restrict__ Pb,
    const float* __restrict__ cob,
    const float* __restrict__ gam, const float* __restrict__ bet,
    const ushort* __restrict__ w1b, const float* __restrict__ b1,
    const ushort* __restrict__ w2b, const float* __restrict__ b2)
{
  __shared__ __align__(16) ushort pool[29952];  // 59904 B
  ushort* sW1 = pool;
  ushort* sW2 = pool + 8192;
  ushort* sH  = pool + 16384;
  ushort* sHf = pool + 25088;
  float*  sF  = (float*)pool;
  int tid = threadIdx.x;
  int g = blockIdx.x;
  size_t tb = (size_t)g*64;

  int wid = tid>>6, ln = tid&63;
  int lr = ln&15, gq = ln>>4;
  int wt = wid>>1, we = wid&1;
  int t0 = wt*16;

  #pragma unroll
  for (int i = 0; i < 2; i++){
    int row = wid*8 + i*4 + (ln>>4);
    gl_lds16(w1b + (size_t)row*128 + (((ln&15) ^ (row&7))<<3),
             &sW1[(wid*8 + i*4)*128]);
  }
  #pragma unroll
  for (int i = 0; i < 2; i++){
    int row = wid*16 + i*8 + (ln>>3);
    gl_lds16(w2b + (size_t)row*512 + (((ln&7) ^ (row&7))<<3),
             &sW2[(wid*16 + i*8)*64]);
  }

  int ttk = tid>>3, s8 = tid&7;
  float* yr = y + (tb+ttk)*128 + s8*16;
  float4 v[4];
  float fmean;
  {
    #pragma unroll
    for (int i = 0; i < 4; i++) v[i] = *(const float4*)(yr + i*4);
    const float* qp = qbuf + (size_t)g*256 + ttk;
    float q0 = qp[0], q1 = qp[64], q2 = qp[128], q3 = qp[192];
    const float* pr = Pb + ((size_t)((g>>10)*64 + ttk))*512 + s8*16;
    #pragma unroll
    for (int i = 0; i < 4; i++){
      float4 p0 = *(const float4*)(pr + i*4);
      float4 p1 = *(const float4*)(pr + 128 + i*4);
      float4 p2 = *(const float4*)(pr + 256 + i*4);
      float4 p3 = *(const float4*)(pr + 384 + i*4);
      float4 c4 = *(const float4*)&cob[s8*16 + i*4];
      v[i].x += c4.x + q0*p0.x+q1*p1.x+q2*p2.x+q3*p3.x;
      v[i].y += c4.y + q0*p0.y+q1*p1.y+q2*p2.y+q3*p3.y;
      v[i].z += c4.z + q0*p0.z+q1*p1.z+q2*p2.z+q3*p3.z;
      v[i].w += c4.w + q0*p0.w+q1*p1.w+q2*p2.w+q3*p3.w;
    }
    float sum = 0.f;
    #pragma unroll
    for (int i = 0; i < 4; i++) sum += v[i].x+v[i].y+v[i].z+v[i].w;
    sum += __shfl_xor(sum,1); sum += __shfl_xor(sum,2); sum += __shfl_xor(sum,4);
    fmean = sum*(1.0f/128.0f);
    float vs = 0.f;
    #pragma unroll
    for (int i = 0; i < 4; i++){
      v[i].x-=fmean; v[i].y-=fmean; v[i].z-=fmean; v[i].w-=fmean;
      vs += v[i].x*v[i].x+v[i].y*v[i].y+v[i].z*v[i].z+v[i].w*v[i].w;
    }
    vs += __shfl_xor(vs,1); vs += __shfl_xor(vs,2); vs += __shfl_xor(vs,4);
    float rstd = rsqrtf(vs*(1.0f/128.0f) + 1e-5f);
    const float* gp = gam + s8*16; const float* bp = bet + s8*16;
    #pragma unroll
    for (int i = 0; i < 2; i++){
      float4 ga = *(const float4*)(gp + i*8),     gb = *(const float4*)(gp + i*8 + 4);
      float4 ba = *(const float4*)(bp + i*8),     bb = *(const float4*)(bp + i*8 + 4);
      float4 va = v[i*2], vb2 = v[i*2+1];
      int4 o;
      o.x = (int)pk2(va.x*rstd*ga.x+ba.x,  va.y*rstd*ga.y+ba.y);
      o.y = (int)pk2(va.z*rstd*ga.z+ba.z,  va.w*rstd*ga.w+ba.w);
      o.z = (int)pk2(vb2.x*rstd*gb.x+bb.x, vb2.y*rstd*gb.y+bb.y);
      o.w = (int)pk2(vb2.z*rstd*gb.z+bb.z, vb2.w*rstd*gb.w+bb.w);
      *(int4*)&sH[ttk*136 + s8*16 + i*8] = o;
    }
  }
  __syncthreads();

  f32x4 acc2[4] = {};

  for (int c = 0; c < 8; c++){
    f32x4 acc1[2] = {};
    #pragma unroll
    for (int ks = 0; ks < 4; ks++){
      bf16x8 bfv = *(const bf16x8*)&sH[(t0+lr)*136 + ks*32 + gq*8];
      #pragma unroll
      for (int i = 0; i < 2; i++){
        int er = we*32 + i*16 + lr;
        bf16x8 afv = *(const bf16x8*)&sW1[er*128 + ((((ks<<2)|gq) ^ (lr&7))<<3)];
        acc1[i] = __builtin_amdgcn_mfma_f32_16x16x32_bf16(afv, bfv, acc1[i], 0, 0, 0);
      }
    }
    #pragma unroll
    for (int i = 0; i < 2; i++){
      float4 bb = *(const float4*)&b1[c*64 + we*32 + i*16 + gq*4];
      ushort4 pk;
      pk.x = bfr(fast_gelu(acc1[i][0] + bb.x));
      pk.y = bfr(fast_gelu(acc1[i][1] + bb.y));
      pk.z = bfr(fast_gelu(acc1[i][2] + bb.z));
      pk.w = bfr(fast_gelu(acc1[i][3] + bb.w));
      *(ushort4*)&sHf[(t0+lr)*72 + we*32 + i*16 + gq*4] = pk;
    }
    __syncthreads();
    if (c < 7){
      #pragma unroll
      for (int i = 0; i < 2; i++){
        int row = wid*8 + i*4 + (ln>>4);
        gl_lds16(w1b + (size_t)(c+1)*8192 + (size_t)row*128 + (((ln&15) ^ (row&7))<<3),
                 &sW1[(wid*8 + i*4)*128]);
      }
    }
    #pragma unroll
    for (int ks = 0; ks < 2; ks++){
      bf16x8 bfv = *(const bf16x8*)&sHf[(t0+lr)*72 + ks*32 + gq*8];
      #pragma unroll
      for (int j = 0; j < 4; j++){
        int dr = we*64 + j*16 + lr;
        bf16x8 afv = *(const bf16x8*)&sW2[dr*64 + ((((ks<<2)|gq) ^ (lr&7))<<3)];
        acc2[j] = __builtin_amdgcn_mfma_f32_16x16x32_bf16(afv, bfv, acc2[j], 0, 0, 0);
      }
    }
    __syncthreads();
    if (c < 7){
      #pragma unroll
      for (int i = 0; i < 2; i++){
        int row = wid*16 + i*8 + (ln>>3);
        gl_lds16(w2b + (size_t)row*512 + (c+1)*64 + (((ln&7) ^ (row&7))<<3),
                 &sW2[(wid*16 + i*8)*64]);
      }
    }
  }

  #pragma unroll
  for (int j = 0; j < 4; j++){
    float4 fo; fo.x=acc2[j][0]; fo.y=acc2[j][1]; fo.z=acc2[j][2]; fo.w=acc2[j][3];
    *(float4*)&sF[(t0+lr)*132 + we*64 + j*16 + gq*4] = fo;
  }
  __syncthreads();
  #pragma unroll
  for (int i = 0; i < 4; i++){
    float4 f = *(const float4*)&sF[ttk*132 + s8*16 + i*4];
    float4 b4 = *(const float4*)&b2[s8*16 + i*4];
    float4 o;
    o.x = v[i].x + fmean + f.x + b4.x;
    o.y = v[i].y + fmean + f.y + b4.y;
    o.z = v[i].z + fmean + f.z + b4.z;
    o.w = v[i].w + fmean + f.w + b4.w;
    *(float4*)(yr + i*4) = o;
  }
}

// ---------------- merged: col-out(l) + FFN(l) + row-attn(l+1) + col-qk(l+1) ----
// y written exactly once (phase C). Row phases reuse the FFN LDS pool.
__global__ __launch_bounds__(512, 2) void k_fr(
    float* __restrict__ y,
    const float* __restrict__ qbuf, const float* __restrict__ Pb,
    const float* __restrict__ cob,
    const float* __restrict__ fgam, const float* __restrict__ fbet,
    const ushort* __restrict__ w1b, const float* __restrict__ b1,
    const ushort* __restrict__ w2b, const float* __restrict__ b2,
    const float* __restrict__ rqw, const float* __restrict__ rqb,
    const float* __restrict__ rkw, const float* __restrict__ rkb,
    const float* __restrict__ rvb_, const float* __restrict__ rvw,
    const float* __restrict__ roW, const float* __restrict__ rob,
    const float* __restrict__ lrg, const float* __restrict__ lrb,
    const float* __restrict__ cqw, const float* __restrict__ cqb,
    const float* __restrict__ ckw, const float* __restrict__ ckb,
    const float* __restrict__ lcg, const float* __restrict__ lcb,
    float2* __restrict__ stats,
    float* __restrict__ qout, float* __restrict__ kout)
{
  __shared__ __align__(16) ushort pool[29952];  // 59904 B
  ushort* sW1 = pool;
  ushort* sW2 = pool + 8192;
  ushort* sH  = pool + 16384;
  ushort* sHf = pool + 25088;
  float*  sF  = (float*)pool;
  // row-phase overlays (pool fully free after epilogue barrier)
  ushort* rh   = pool;                    // bytes [0,17408): bf16 h tile 64xHSTRB
  float*  rw4  = (float*)(pool + 8704);   // [17408,25600): rqw|rkw|cqw|ckw
  float*  rQ   = (float*)(pool + 12800);  // [25600,26624)
  float*  rK   = (float*)(pool + 13312);  // [26624,27648)
  float*  rhkP = (float*)(pool + 13824);  // [27648,29696)
  float*  rktv = (float*)(pool + 14848);  // [29696,30208)
  int tid = threadIdx.x;
  int g = blockIdx.x;
  size_t tb = (size_t)g*64;

  int wid = tid>>6, ln = tid&63;
  int lr = ln&15, gq = ln>>4;
  int wt = wid>>1, we = wid&1;
  int t0 = wt*16;

  #pragma unroll
  for (int i = 0; i < 2; i++){
    int row = wid*8 + i*4 + (ln>>4);
    gl_lds16(w1b + (size_t)row*128 + (((ln&15) ^ (row&7))<<3),
             &sW1[(wid*8 + i*4)*128]);
  }
  #pragma unroll
  for (int i = 0; i < 2; i++){
    int row = wid*16 + i*8 + (ln>>3);
    gl_lds16(w2b + (size_t)row*512 + (((ln&7) ^ (row&7))<<3),
             &sW2[(wid*16 + i*8)*64]);
  }

  int ttk = tid>>3, s8 = tid&7;
  float* yr = y + (tb+ttk)*128 + s8*16;
  float4 v[4];
  float fmean;
  {
    #pragma unroll
    for (int i = 0; i < 4; i++) v[i] = *(const float4*)(yr + i*4);
    const float* qp = qbuf + (size_t)g*256 + ttk;
    float q0 = qp[0], q1 = qp[64], q2 = qp[128], q3 = qp[192];
    const float* pr = Pb + ((size_t)((g>>10)*64 + ttk))*512 + s8*16;
    #pragma unroll
    for (int i = 0; i < 4; i++){
      float4 p0 = *(const float4*)(pr + i*4);
      float4 p1 = *(const float4*)(pr + 128 + i*4);
      float4 p2 = *(const float4*)(pr + 256 + i*4);
      float4 p3 = *(const float4*)(pr + 384 + i*4);
      float4 c4 = *(const float4*)&cob[s8*16 + i*4];
      v[i].x += c4.x + q0*p0.x+q1*p1.x+q2*p2.x+q3*p3.x;
      v[i].y += c4.y + q0*p0.y+q1*p1.y+q2*p2.y+q3*p3.y;
      v[i].z += c4.z + q0*p0.z+q1*p1.z+q2*p2.z+q3*p3.z;
      v[i].w += c4.w + q0*p0.w+q1*p1.w+q2*p2.w+q3*p3.w;
    }
    float sum = 0.f;
    #pragma unroll
    for (int i = 0; i < 4; i++) sum += v[i].x+v[i].y+v[i].z+v[i].w;
    sum += __shfl_xor(sum,1); sum += __shfl_xor(sum,2); sum += __shfl_xor(sum,4);
    fmean = sum*(1.0f/128.0f);
    float vs = 0.f;
    #pragma unroll
    for (int i = 0; i < 4; i++){
      v[i].x-=fmean; v[i].y-=fmean; v[i].z-=fmean; v[i].w-=fmean;
      vs += v[i].x*v[i].x+v[i].y*v[i].y+v[i].z*v[i].z+v[i].w*v[i].w;
    }
    vs += __shfl_xor(vs,1); vs += __shfl_xor(vs,2); vs += __shfl_xor(vs,4);
    float rstd = rsqrtf(vs*(1.0f/128.0f) + 1e-5f);
    const float* gp = fgam + s8*16; const float* bp = fbet + s8*16;
    #pragma unroll
    for (int i = 0; i < 2; i++){
      float4 ga = *(const float4*)(gp + i*8),     gb = *(const float4*)(gp + i*8 + 4);
      float4 ba = *(const float4*)(bp + i*8),     bb = *(const float4*)(bp + i*8 + 4);
      float4 va = v[i*2], vb2 = v[i*2+1];
      int4 o;
      o.x = (int)pk2(va.x*rstd*ga.x+ba.x,  va.y*rstd*ga.y+ba.y);
      o.y = (int)pk2(va.z*rstd*ga.z+ba.z,  va.w*rstd*ga.w+ba.w);
      o.z = (int)pk2(vb2.x*rstd*gb.x+bb.x, vb2.y*rstd*gb.y+bb.y);
      o.w = (int)pk2(vb2.z*rstd*gb.z+bb.z, vb2.w*rstd*gb.w+bb.w);
      *(int4*)&sH[ttk*136 + s8*16 + i*8] = o;
    }
  }
  __syncthreads();

  f32x4 acc2[4] = {};
  for (int c = 0; c < 8; c++){
    f32x4 acc1[2] = {};
    #pragma unroll
    for (int ks = 0; ks < 4; ks++){
      bf16x8 bfv = *(const bf16x8*)&sH[(t0+lr)*136 + ks*32 + gq*8];
      #pragma unroll
      for (int i = 0; i < 2; i++){
        int er = we*32 + i*16 + lr;
        bf16x8 afv = *(const bf16x8*)&sW1[er*128 + ((((ks<<2)|gq) ^ (lr&7))<<3)];
        acc1[i] = __builtin_amdgcn_mfma_f32_16x16x32_bf16(afv, bfv, acc1[i], 0, 0, 0);
      }
    }
    #pragma unroll
    for (int i = 0; i < 2; i++){
      float4 bb = *(const float4*)&b1[c*64 + we*32 + i*16 + gq*4];
      ushort4 pk;
      pk.x = bfr(fast_gelu(acc1[i][0] + bb.x));
      pk.y = bfr(fast_gelu(acc1[i][1] + bb.y));
      pk.z = bfr(fast_gelu(acc1[i][2] + bb.z));
      pk.w = bfr(fast_gelu(acc1[i][3] + bb.w));
      *(ushort4*)&sHf[(t0+lr)*72 + we*32 + i*16 + gq*4] = pk;
    }
    __syncthreads();
    if (c < 7){
      #pragma unroll
      for (int i = 0; i < 2; i++){
        int row = wid*8 + i*4 + (ln>>4);
        gl_lds16(w1b + (size_t)(c+1)*8192 + (size_t)row*128 + (((ln&15) ^ (row&7))<<3),
                 &sW1[(wid*8 + i*4)*128]);
      }
    }
    #pragma unroll
    for (int ks = 0; ks < 2; ks++){
      bf16x8 bfv = *(const bf16x8*)&sHf[(t0+lr)*72 + ks*32 + gq*8];
      #pragma unroll
      for (int j = 0; j < 4; j++){
        int dr = we*64 + j*16 + lr;
        bf16x8 afv = *(const bf16x8*)&sW2[dr*64 + ((((ks<<2)|gq) ^ (lr&7))<<3)];
        acc2[j] = __builtin_amdgcn_mfma_f32_16x16x32_bf16(afv, bfv, acc2[j], 0, 0, 0);
      }
    }
    __syncthreads();
    if (c < 7){
      #pragma unroll
      for (int i = 0; i < 2; i++){
        int row = wid*16 + i*8 + (ln>>3);
        gl_lds16(w2b + (size_t)row*512 + (c+1)*64 + (((ln&7) ^ (row&7))<<3),
                 &sW2[(wid*16 + i*8)*64]);
      }
    }
  }

  // ---- FFN epilogue: y_new kept in v[] (no global write) ----
  #pragma unroll
  for (int j = 0; j < 4; j++){
    float4 fo; fo.x=acc2[j][0]; fo.y=acc2[j][1]; fo.z=acc2[j][2]; fo.w=acc2[j][3];
    *(float4*)&sF[(t0+lr)*132 + we*64 + j*16 + gq*4] = fo;
  }
  __syncthreads();
  #pragma unroll
  for (int i = 0; i < 4; i++){
    float4 f = *(const float4*)&sF[ttk*132 + s8*16 + i*4];
    float4 b4 = *(const float4*)&b2[s8*16 + i*4];
    v[i].x += fmean + f.x + b4.x;
    v[i].y += fmean + f.y + b4.y;
    v[i].z += fmean + f.z + b4.z;
    v[i].w += fmean + f.w + b4.w;
  }
  __syncthreads();   // all sF reads done; pool free for row overlays

  // ---- stage next-layer q/k weights (lands under A') ----
  {
    const float* wsrc = (wid<2)?rqw:(wid<4)?rkw:(wid<6)?cqw:ckw;
    gl_lds16(wsrc + (wid&1)*256 + ln*4, &rw4[(size_t)wid*256]);
  }

  // ---- A': row LN (lrg) of y_new -> rh (bf16) ----
  float rmean;
  {
    float sum = 0.f;
    #pragma unroll
    for (int i = 0; i < 4; i++) sum += v[i].x+v[i].y+v[i].z+v[i].w;
    sum += __shfl_xor(sum,1); sum += __shfl_xor(sum,2); sum += __shfl_xor(sum,4);
    rmean = sum*(1.0f/128.0f);
    float vs = 0.f;
    #pragma unroll
    for (int i = 0; i < 4; i++){
      v[i].x-=rmean; v[i].y-=rmean; v[i].z-=rmean; v[i].w-=rmean;
      vs += v[i].x*v[i].x+v[i].y*v[i].y+v[i].z*v[i].z+v[i].w*v[i].w;
    }
    vs += __shfl_xor(vs,1); vs += __shfl_xor(vs,2); vs += __shfl_xor(vs,4);
    float rstd = rsqrtf(vs*(1.0f/128.0f) + 1e-5f);
    const float* gp = lrg + s8*16; const float* bp = lrb + s8*16;
    ushort* hrow = &rh[ttk*HSTRB + s8*16];
    #pragma unroll
    for (int i = 0; i < 2; i++){
      float4 ga = *(const float4*)(gp + i*8),  gb = *(const float4*)(gp + i*8 + 4);
      float4 ba = *(const float4*)(bp + i*8),  bb = *(const float4*)(bp + i*8 + 4);
      float4 va = v[i*2], vb2 = v[i*2+1];
      int4 o;
      o.x = (int)pk2(va.x*rstd*ga.x+ba.x,  va.y*rstd*ga.y+ba.y);
      o.y = (int)pk2(va.z*rstd*ga.z+ba.z,  va.w*rstd*ga.w+ba.w);
      o.z = (int)pk2(vb2.x*rstd*gb.x+bb.x, vb2.y*rstd*gb.y+bb.y);
      o.w = (int)pk2(vb2.z*rstd*gb.z+bb.z, vb2.w*rstd*gb.w+bb.w);
      *(int4*)&hrow[i*8] = o;
    }
  }
  __syncthreads();   // drains rw4 stage (vmcnt) + rh writes

  // ---- B1 (tid<256): row q,k + normalize ----
  if (tid < 256){
    int h = tid>>6, n = tid&63;
    float qr = rqb[h], kr = rkb[h];
    const int4* hp = (const int4*)&rh[n*HSTRB];
    const float4* qwp = (const float4*)&rw4[h*128];
    const float4* kwp = (const float4*)&rw4[512 + h*128];
    #pragma unroll 4
    for (int j=0;j<16;j++){
      int4 h8 = hp[j];
      float4 qa = qwp[2*j], qb4 = qwp[2*j+1];
      float4 ka = kwp[2*j], kb4 = kwp[2*j+1];
      float h0=bflo((u32)h8.x), h1=bfhi((u32)h8.x);
      float h2=bflo((u32)h8.y), h3=bfhi((u32)h8.y);
      float h4=bflo((u32)h8.z), h5=bfhi((u32)h8.z);
      float h6=bflo((u32)h8.w), h7=bfhi((u32)h8.w);
      qr += h0*qa.x+h1*qa.y+h2*qa.z+h3*qa.w + h4*qb4.x+h5*qb4.y+h6*qb4.z+h7*qb4.w;
      kr += h0*ka.x+h1*ka.y+h2*ka.z+h3*ka.w + h4*kb4.x+h5*kb4.y+h6*kb4.z+h7*kb4.w;
    }
    qr = qr > 0.f ? qr + 1.f : __expf(qr);
    kr = kr > 0.f ? kr + 1.f : __expf(kr);
    float qs = qr; for (int m=32;m>=1;m>>=1) qs += __shfl_xor(qs, m);
    float ks = kr; for (int m=32;m>=1;m>>=1) ks += __shfl_xor(ks, m);
    rQ[h*64+n] = qr * (64.f/qs);
    rK[h*64+n] = kr * (1.f/ks);
  }
  __syncthreads();
  // ---- B2 (512): hk[h][d] ----
  {
    int hh = tid>>7, d = tid&127;
    float acc = 0.f;
    #pragma unroll 4
    for (int nn=0;nn<64;nn++)
      acc += rK[hh*64+nn]*bflo((u32)rh[nn*HSTRB+d]);
    rhkP[hh*128+d] = acc;
  }
  __syncthreads();
  // ---- B3 (tid<128): ktv ----
  if (tid < 128){
    float acc = rvb_[tid];
    const float4* vr = (const float4*)(rvw + (size_t)tid*128);
    const float4* hp2 = (const float4*)(rhkP + (tid>>5)*128);
    #pragma unroll 8
    for (int j=0;j<32;j++){
      float4 a = vr[j], bq = hp2[j];
      acc += a.x*bq.x + a.y*bq.y + a.z*bq.z + a.w*bq.w;
    }
    rktv[tid] = acc;
  }
  __syncthreads();
  // ---- B4 (512): P[h][e] -> rhkP (hk dead) ----
  {
    int hh = tid>>7, e = tid&127;
    float acc = 0.f;
    const float4* orow = (const float4*)(roW + (size_t)e*128 + hh*32);
    const float4* kt = (const float4*)(rktv + hh*32);
    #pragma unroll
    for (int j=0;j<8;j++){
      float4 a = orow[j], bq = kt[j];
      acc += a.x*bq.x + a.y*bq.y + a.z*bq.z + a.w*bq.w;
    }
    rhkP[hh*128+e] = acc;
  }
  __syncthreads();
  // ---- C: y_final = y_new + rob + q·P  (single global y write) ----
  {
    float q0=rQ[ttk], q1=rQ[64+ttk], q2=rQ[128+ttk], q3=rQ[192+ttk];
    #pragma unroll
    for (int i=0;i<4;i++){
      float4 p0 = *(const float4*)&rhkP[s8*16 + i*4];
      float4 p1 = *(const float4*)&rhkP[128 + s8*16 + i*4];
      float4 p2 = *(const float4*)&rhkP[256 + s8*16 + i*4];
      float4 p3 = *(const float4*)&rhkP[384 + s8*16 + i*4];
      float4 o4 = *(const float4*)&rob[s8*16 + i*4];
      v[i].x += rmean + o4.x + q0*p0.x+q1*p1.x+q2*p2.x+q3*p3.x;
      v[i].y += rmean + o4.y + q0*p0.y+q1*p1.y+q2*p2.y+q3*p3.y;
      v[i].z += rmean + o4.z + q0*p0.z+q1*p1.z+q2*p2.z+q3*p3.z;
      v[i].w += rmean + o4.w + q0*p0.w+q1*p1.w+q2*p2.w+q3*p3.w;
      *(float4*)(yr + i*4) = v[i];
    }
  }
  // ---- D0: col LN stats + col-norm h -> rh ----
  {
    float sum2 = 0.f;
    #pragma unroll
    for (int i=0;i<4;i++) sum2 += v[i].x+v[i].y+v[i].z+v[i].w;
    sum2 += __shfl_xor(sum2,1); sum2 += __shfl_xor(sum2,2); sum2 += __shfl_xor(sum2,4);
    float cmean = sum2*(1.0f/128.0f);
    float cvs = 0.f;
    #pragma unroll
    for (int i=0;i<4;i++){
      v[i].x-=cmean; v[i].y-=cmean; v[i].z-=cmean; v[i].w-=cmean;
      cvs += v[i].x*v[i].x+v[i].y*v[i].y+v[i].z*v[i].z+v[i].w*v[i].w;
    }
    cvs += __shfl_xor(cvs,1); cvs += __shfl_xor(cvs,2); cvs += __shfl_xor(cvs,4);
    float crstd = rsqrtf(cvs*(1.0f/128.0f) + 1e-5f);
    if (s8 == 0) stats[(size_t)g*64 + ttk] = make_float2(cmean, crstd);
    const float* gp = lcg + s8*16; const float* bp = lcb + s8*16;
    ushort* hrow = &rh[ttk*HSTRB + s8*16];
    #pragma unroll
    for (int i = 0; i < 2; i++){
      float4 ga = *(const float4*)(gp + i*8),  gb = *(const float4*)(gp + i*8 + 4);
      float4 ba = *(const float4*)(bp + i*8),  bb = *(const float4*)(bp + i*8 + 4);
      float4 va = v[i*2], vb2 = v[i*2+1];
      int4 o;
      o.x = (int)pk2(va.x*crstd*ga.x+ba.x,  va.y*crstd*ga.y+ba.y);
      o.y = (int)pk2(va.z*crstd*ga.z+ba.z,  va.w*crstd*ga.w+ba.w);
      o.z = (int)pk2(vb2.x*crstd*gb.x+bb.x, vb2.y*crstd*gb.y+bb.y);
      o.w = (int)pk2(vb2.z*crstd*gb.z+bb.z, vb2.w*crstd*gb.w+bb.w);
      *(int4*)&hrow[i*8] = o;
    }
  }
  __syncthreads();
  // ---- D1 (tid<256): col raw q,k ----
  if (tid < 256){
    int h = tid>>6, n = tid&63;
    float qv = cqb[h], kv = ckb[h];
    const int4* hp = (const int4*)&rh[n*HSTRB];
    const float4* qwp = (const float4*)&rw4[1024 + h*128];
    const float4* kwp = (const float4*)&rw4[1536 + h*128];
    #pragma unroll 4
    for (int j=0;j<16;j++){
      int4 h8 = hp[j];
      float4 qa = qwp[2*j], qb4 = qwp[2*j+1];
      float4 ka = kwp[2*j], kb4 = kwp[2*j+1];
      float h0=bflo((u32)h8.x), h1=bfhi((u32)h8.x);
      float h2=bflo((u32)h8.y), h3=bfhi((u32)h8.y);
      float h4=bflo((u32)h8.z), h5=bfhi((u32)h8.z);
      float h6=bflo((u32)h8.w), h7=bfhi((u32)h8.w);
      qv += h0*qa.x+h1*qa.y+h2*qa.z+h3*qa.w + h4*qb4.x+h5*qb4.y+h6*qb4.z+h7*qb4.w;
      kv += h0*ka.x+h1*ka.y+h2*ka.z+h3*ka.w + h4*kb4.x+h5*kb4.y+h6*kb4.z+h7*kb4.w;
    }
    qv = qv > 0.f ? qv + 1.f : __expf(qv);
    kv = kv > 0.f ? kv + 1.f : __expf(kv);
    size_t o = (size_t)g*256 + tid;
    qout[o] = qv; kout[o] = kv;
  }
}

// ---------------- head: xb partials (4 l-slices) + reduce ----------------
__global__ __launch_bounds__(128) void k_xbp(const float* __restrict__ y,
                                             float* __restrict__ xbq){
  int gg = blockIdx.x;   // (b*64+n)*4 + s
  int s = gg & 3, n = (gg>>2) & 63, b = gg>>8;
  int d = threadIdx.x;
  float acc = 0.f;
  int l0 = s*256 + (s==0 ? 1 : 0);
  const float* p = y + (((size_t)b*1024 + l0)*64 + n)*128 + d;
  for (int l = l0; l < s*256+256; l++){ acc += *p; p += 64*128; }
  xbq[(size_t)gg*128 + d] = acc;
}
__global__ __launch_bounds__(128) void k_xbr(const float* __restrict__ xbq,
                                             float* __restrict__ xb){
  int gg = blockIdx.x;   // b*64+n
  int d = threadIdx.x;
  const float* q = xbq + (size_t)gg*512;
  xb[(size_t)gg*128 + d] = (q[d] + q[128+d] + q[256+d] + q[384+d]) * (1.0f/1023.0f);
}

// ---------------- head: pairwise distances ----------------
__global__ __launch_bounds__(64) void k_dist(const float* __restrict__ xb,
                                             float* __restrict__ out){
  int p = blockIdx.x;           // b*2016 + pair
  int b = p >= 2016 ? 1 : 0;
  int pr = p - b*2016;
  int i0 = (int)((1.0f + sqrtf(1.0f + 8.0f*(float)pr))*0.5f);
  while (i0*(i0-1)/2 > pr) i0--;
  while ((i0+1)*i0/2 <= pr) i0++;
  int i1 = pr - i0*(i0-1)/2;
  int lane = threadIdx.x;
  const float* xa = xb + ((size_t)b*64 + i0)*128;
  const float* xc = xb + ((size_t)b*64 + i1)*128;
  float d0 = xa[lane]-xc[lane], d1 = xa[lane+64]-xc[lane+64];
  float s = d0*d0 + d1*d1;
  for (int m=32;m>=1;m>>=1) s += __shfl_xor(s, m);
  if (lane == 0) out[p] = sqrtf(s + 1e-8f);
}

extern "C" void kernel_launch(void* const* d_in, const int* in_sizes, int n_in,
                              void* d_out, int out_size, void* d_ws, size_t ws_size,
                              hipStream_t stream){
  const float* x    = (const float*)d_in[0];
  const float* rq_w = (const float*)d_in[1];  const float* rq_b = (const float*)d_in[2];
  const float* rk_w = (const float*)d_in[3];  const float* rk_b = (const float*)d_in[4];
  const float* rv_w = (const float*)d_in[5];  const float* rv_b = (const float*)d_in[6];
  const float* ro_w = (const float*)d_in[7];  const float* ro_b = (const float*)d_in[8];
  const float* cq_w = (const float*)d_in[9];  const float* cq_b = (const float*)d_in[10];
  const float* ck_w = (const float*)d_in[11]; const float* ck_b = (const float*)d_in[12];
  const float* cv_w = (const float*)d_in[13]; const float* cv_b = (const float*)d_in[14];
  const float* co_w = (const float*)d_in[15]; const float* co_b = (const float*)d_in[16];
  const float* lrg  = (const float*)d_in[17]; const float* lrb  = (const float*)d_in[18];
  const float* lcg  = (const float*)d_in[19]; const float* lcb  = (const float*)d_in[20];
  const float* lfg  = (const float*)d_in[21]; const float* lfb  = (const float*)d_in[22];
  const float* f1w  = (const float*)d_in[23]; const float* f1b  = (const float*)d_in[24];
  const float* f2w  = (const float*)d_in[25]; const float* f2b  = (const float*)d_in[26];

  float* ws = (float*)d_ws;
  float*  y   = ws;                           // 16777216
  float2* st  = (float2*)(ws + 16777216);     // 262144 floats
  float*  qb_ = ws + 17039360;                // 524288
  float*  kb_ = ws + 17563648;                // 524288
  float*  Pb  = ws + 18087936;                // 1048576
  float*  s1p = ws + 19136512;                // 524288
  float*  xb  = ws + 19661824;                // 16384
  ushort* w1b = (ushort*)(ws + 19678208);     // 262144 ushorts
  ushort* w2b = (ushort*)(ws + 19809280);     // 262144 ushorts
  float*  xbq = ws + 19940352;                // 65536
  float*  Ab  = ws + 20005888;                // 4096
  float*  Bb  = ws + 20009984;                // 4096
  float*  qsp = ws + 20014080;                // 4096

  k_transpose<<<dim3(2048), dim3(256), 0, stream>>>(x, y);
  k_cvt<<<dim3(256), dim3(256), 0, stream>>>(f1w, w1b, 65536);
  k_cvt<<<dim3(256), dim3(256), 0, stream>>>(f2w, w2b, 65536);
  // layer 0 row
  k_row<<<dim3(2048), dim3(256), 0, stream>>>(y,
      rq_w, rq_b, rk_w, rk_b, rv_w, rv_b, ro_w, ro_b,
      lrg, lrb, cq_w, cq_b, ck_w, ck_b, lcg, lcb,
      st, qb_, kb_);
  for (int l = 0; l < LCNT; l++){
    k_qsum<<<dim3(16), dim3(256), 0, stream>>>(qb_, qsp);
    k_col_s1<<<dim3(1024), dim3(256), 0, stream>>>(y, st, kb_, s1p, Ab, Bb);
    k_col_ktvP<<<dim3(128), dim3(256), 0, stream>>>(s1p, Ab, Bb, qsp,
        cv_w + (size_t)l*16384, cv_b + l*128, co_w + (size_t)l*16384,
        lcg + l*128, lcb + l*128, Pb);
    if (l < LCNT-1){
      int m = l+1;
      k_fr<<<dim3(2048), dim3(512), 0, stream>>>(y, qb_, Pb, co_b + l*128,
          lfg + l*128, lfb + l*128,
          w1b + (size_t)l*65536, f1b + l*512, w2b + (size_t)l*65536, f2b + l*128,
          rq_w + m*512, rq_b + m*4, rk_w + m*512, rk_b + m*4,
          rv_b + m*128, rv_w + (size_t)m*16384,
          ro_w + (size_t)m*16384, ro_b + m*128,
          lrg + m*128, lrb + m*128,
          cq_w + m*512, cq_b + m*4, ck_w + m*512, ck_b + m*4,
          lcg + m*128, lcb + m*128,
          st, qb_, kb_);
    } else {
      k_ffn<<<dim3(2048), dim3(512), 0, stream>>>(y, qb_, Pb, co_b + l*128,
          lfg + l*128, lfb + l*128,
          w1b + (size_t)l*65536, f1b + l*512, w2b + (size_t)l*65536, f2b + l*128);
    }
  }
  k_xbp<<<dim3(512), dim3(128), 0, stream>>>(y, xbq);
  k_xbr<<<dim3(128), dim3(128), 0, stream>>>(xbq, xb);
  k_dist<<<dim3(4032), dim3(64), 0, stream>>>(xb, (float*)d_out);
}

// Round 14
// 983.628 us; speedup vs baseline: 1.0897x; 1.0897x over previous
//
#include <hip/hip_runtime.h>
#include <math.h>

#define LCNT 4

typedef float f32x4 __attribute__((ext_vector_type(4)));
typedef short bf16x8 __attribute__((ext_vector_type(8)));
typedef unsigned int u32;

__device__ __forceinline__ ushort bfr(float x){
  unsigned int b = __float_as_uint(x);
  return (ushort)((b + 0x7FFFu + ((b>>16)&1u)) >> 16);
}
__device__ __forceinline__ unsigned int pk2(float a, float b){
  return (unsigned int)bfr(a) | ((unsigned int)bfr(b)<<16);
}
__device__ __forceinline__ float bflo(u32 u){ return __uint_as_float(u<<16); }
__device__ __forceinline__ float bfhi(u32 u){ return __uint_as_float(u & 0xffff0000u); }
__device__ __forceinline__ float fast_gelu(float v){
  float v2 = v*v;
  float u = v*(-1.5957691f - 0.0713548162f*v2);
  float e = __expf(u);
  return v*__builtin_amdgcn_rcpf(1.f + e);
}
__device__ __forceinline__ void gl_lds16(const void* g, void* l){
  __builtin_amdgcn_global_load_lds(
      (const __attribute__((address_space(1))) u32*)g,
      (__attribute__((address_space(3))) u32*)l, 16, 0, 0);
}

// ---------------- transpose x[B,D,L,N] -> y[B,L,N,D] ----------------
__global__ __launch_bounds__(256) void k_transpose(const float* __restrict__ x,
                                                   float* __restrict__ y){
  int g = blockIdx.x;            // b*1024 + l
  int b = g >> 10, l = g & 1023;
  __shared__ float sh[128*65];
  for (int idx = threadIdx.x; idx < 128*64; idx += 256){
    int d = idx >> 6, n = idx & 63;
    sh[d*65+n] = x[(((size_t)b*128 + d)*1024 + l)*64 + n];
  }
  __syncthreads();
  for (int idx = threadIdx.x; idx < 128*64; idx += 256){
    int n = idx >> 7, d = idx & 127;
    y[((size_t)g*64 + n)*128 + d] = sh[d*65+n];
  }
}

// ---------------- fp32 -> bf16 weight conversion ----------------
__global__ __launch_bounds__(256) void k_cvt(const float* __restrict__ src,
                                             ushort* __restrict__ dst, int n4){
  int i = blockIdx.x*256 + threadIdx.x;
  if (i < n4){
    float4 v = ((const float4*)src)[i];
    ushort4 p; p.x=bfr(v.x); p.y=bfr(v.y); p.z=bfr(v.z); p.w=bfr(v.w);
    ((ushort4*)dst)[i] = p;
  }
}

// ---------------- fused per-(b,l): row LN + row attn + residual
//   + col LN stats + col raw q,k.  512 threads (8 waves), bf16 h tile,
//   LDS 30.2KB -> 4 blocks/CU x 8 waves = 32 waves/CU. ----
#define HSTRB 136   // ushort stride (rows 16B-aligned)
__global__ __launch_bounds__(512, 4) void k_row(
    float* __restrict__ y,
    const float* __restrict__ rqw, const float* __restrict__ rqb,
    const float* __restrict__ rkw, const float* __restrict__ rkb,
    const float* __restrict__ rvw, const float* __restrict__ rvb,
    const float* __restrict__ roW, const float* __restrict__ rob,
    const float* __restrict__ lrg, const float* __restrict__ lrb,
    const float* __restrict__ cqw, const float* __restrict__ cqb,
    const float* __restrict__ ckw, const float* __restrict__ ckb,
    const float* __restrict__ lcg, const float* __restrict__ lcb,
    float2* __restrict__ stats,
    float* __restrict__ qout, float* __restrict__ kout)
{
  int g = blockIdx.x;
  __shared__ __align__(16) ushort sh_h[64*HSTRB];   // 17408 B
  __shared__ __align__(16) float sh_w4[2048];       // 8192 B
  __shared__ float sh_q[256], sh_k[256];
  __shared__ __align__(16) float sh_hkP[512];
  __shared__ __align__(16) float sh_ktv[128];
  int tid = threadIdx.x;
  int wid = tid>>6, ln = tid&63;

  // ---- stage q/k weights (8 waves, lands under LN) ----
  {
    const float* wsrc = (wid<2)?rqw:(wid<4)?rkw:(wid<6)?cqw:ckw;
    gl_lds16(wsrc + (wid&1)*256 + ln*4, &sh_w4[(size_t)wid*256]);
  }

  // ---- A: load raw tile + row LN -> sh_h (bf16), 8 thr/token ----
  int ttk = tid>>3, s8 = tid&7;
  float* yr = y + ((size_t)g*64 + ttk)*128 + s8*16;
  float4 v[4];
  float rmean;
  {
    #pragma unroll
    for (int i = 0; i < 4; i++) v[i] = *(const float4*)(yr + i*4);
    float sum = 0.f;
    #pragma unroll
    for (int i = 0; i < 4; i++) sum += v[i].x+v[i].y+v[i].z+v[i].w;
    sum += __shfl_xor(sum,1); sum += __shfl_xor(sum,2); sum += __shfl_xor(sum,4);
    rmean = sum*(1.0f/128.0f);
    float vs = 0.f;
    #pragma unroll
    for (int i = 0; i < 4; i++){
      v[i].x-=rmean; v[i].y-=rmean; v[i].z-=rmean; v[i].w-=rmean;
      vs += v[i].x*v[i].x+v[i].y*v[i].y+v[i].z*v[i].z+v[i].w*v[i].w;
    }
    vs += __shfl_xor(vs,1); vs += __shfl_xor(vs,2); vs += __shfl_xor(vs,4);
    float rstd = rsqrtf(vs*(1.0f/128.0f) + 1e-5f);
    const float* gp = lrg + s8*16; const float* bp = lrb + s8*16;
    ushort* hrow = &sh_h[ttk*HSTRB + s8*16];
    #pragma unroll
    for (int i = 0; i < 2; i++){
      float4 ga = *(const float4*)(gp + i*8),  gb = *(const float4*)(gp + i*8 + 4);
      float4 ba = *(const float4*)(bp + i*8),  bb = *(const float4*)(bp + i*8 + 4);
      float4 va = v[i*2], vb2 = v[i*2+1];
      int4 o;
      o.x = (int)pk2(va.x*rstd*ga.x+ba.x,  va.y*rstd*ga.y+ba.y);
      o.y = (int)pk2(va.z*rstd*ga.z+ba.z,  va.w*rstd*ga.w+ba.w);
      o.z = (int)pk2(vb2.x*rstd*gb.x+bb.x, vb2.y*rstd*gb.y+bb.y);
      o.w = (int)pk2(vb2.z*rstd*gb.z+bb.z, vb2.w*rstd*gb.w+bb.w);
      *(int4*)&hrow[i*8] = o;
    }
  }
  __syncthreads();   // drains weight stage (vmcnt) + sh_h writes

  // ---- B1 (tid<256): row q,k + normalize ----
  if (tid < 256){
    int h = tid>>6, n = tid&63;
    float qr = rqb[h], kr = rkb[h];
    const int4* hp = (const int4*)&sh_h[n*HSTRB];
    const float4* qwp = (const float4*)&sh_w4[h*128];
    const float4* kwp = (const float4*)&sh_w4[512 + h*128];
    #pragma unroll 4
    for (int j=0;j<16;j++){
      int4 h8 = hp[j];
      float4 qa = qwp[2*j], qb4 = qwp[2*j+1];
      float4 ka = kwp[2*j], kb4 = kwp[2*j+1];
      float h0=bflo((u32)h8.x), h1=bfhi((u32)h8.x);
      float h2=bflo((u32)h8.y), h3=bfhi((u32)h8.y);
      float h4=bflo((u32)h8.z), h5=bfhi((u32)h8.z);
      float h6=bflo((u32)h8.w), h7=bfhi((u32)h8.w);
      qr += h0*qa.x+h1*qa.y+h2*qa.z+h3*qa.w + h4*qb4.x+h5*qb4.y+h6*qb4.z+h7*qb4.w;
      kr += h0*ka.x+h1*ka.y+h2*ka.z+h3*ka.w + h4*kb4.x+h5*kb4.y+h6*kb4.z+h7*kb4.w;
    }
    qr = qr > 0.f ? qr + 1.f : __expf(qr);
    kr = kr > 0.f ? kr + 1.f : __expf(kr);
    float qs = qr; for (int m=32;m>=1;m>>=1) qs += __shfl_xor(qs, m);
    float ks = kr; for (int m=32;m>=1;m>>=1) ks += __shfl_xor(ks, m);
    sh_q[h*64+n] = qr * (64.f/qs);
    sh_k[h*64+n] = kr * (1.f/ks);
  }
  __syncthreads();
  // ---- B2 (512): hk[h][d] ----
  {
    int hh = tid>>7, d = tid&127;
    float acc = 0.f;
    #pragma unroll 4
    for (int nn=0;nn<64;nn++)
      acc += sh_k[hh*64+nn]*bflo((u32)sh_h[nn*HSTRB+d]);
    sh_hkP[hh*128+d] = acc;
  }
  __syncthreads();
  // ---- B3 (tid<128): ktv[e] ----
  if (tid < 128){
    float acc = rvb[tid];
    const float4* vr = (const float4*)(rvw + (size_t)tid*128);
    const float4* hp2 = (const float4*)(sh_hkP + (tid>>5)*128);
    #pragma unroll 8
    for (int j=0;j<32;j++){
      float4 a = vr[j], bq = hp2[j];
      acc += a.x*bq.x + a.y*bq.y + a.z*bq.z + a.w*bq.w;
    }
    sh_ktv[tid] = acc;
  }
  __syncthreads();
  // ---- B4 (512): P[h][e] -> sh_hkP (hk dead) ----
  {
    int hh = tid>>7, e = tid&127;
    float acc = 0.f;
    const float4* orow = (const float4*)(roW + (size_t)e*128 + hh*32);
    const float4* kt = (const float4*)(sh_ktv + hh*32);
    #pragma unroll
    for (int j=0;j<8;j++){
      float4 a = orow[j], bq = kt[j];
      acc += a.x*bq.x + a.y*bq.y + a.z*bq.z + a.w*bq.w;
    }
    sh_hkP[hh*128+e] = acc;
  }
  __syncthreads();
  // ---- C: y_new = raw + ob + q.P  (single y write) ----
  {
    float q0=sh_q[ttk], q1=sh_q[64+ttk], q2=sh_q[128+ttk], q3=sh_q[192+ttk];
    #pragma unroll
    for (int i=0;i<4;i++){
      float4 p0 = *(const float4*)&sh_hkP[s8*16 + i*4];
      float4 p1 = *(const float4*)&sh_hkP[128 + s8*16 + i*4];
      float4 p2 = *(const float4*)&sh_hkP[256 + s8*16 + i*4];
      float4 p3 = *(const float4*)&sh_hkP[384 + s8*16 + i*4];
      float4 o4 = *(const float4*)&rob[s8*16 + i*4];
      v[i].x += rmean + o4.x + q0*p0.x+q1*p1.x+q2*p2.x+q3*p3.x;
      v[i].y += rmean + o4.y + q0*p0.y+q1*p1.y+q2*p2.y+q3*p3.y;
      v[i].z += rmean + o4.z + q0*p0.z+q1*p1.z+q2*p2.z+q3*p3.z;
      v[i].w += rmean + o4.w + q0*p0.w+q1*p1.w+q2*p2.w+q3*p3.w;
      *(float4*)(yr + i*4) = v[i];
    }
  }
  // ---- D0: col LN stats + col-norm h -> sh_h ----
  {
    float sum2 = 0.f;
    #pragma unroll
    for (int i=0;i<4;i++) sum2 += v[i].x+v[i].y+v[i].z+v[i].w;
    sum2 += __shfl_xor(sum2,1); sum2 += __shfl_xor(sum2,2); sum2 += __shfl_xor(sum2,4);
    float cmean = sum2*(1.0f/128.0f);
    float cvs = 0.f;
    #pragma unroll
    for (int i=0;i<4;i++){
      v[i].x-=cmean; v[i].y-=cmean; v[i].z-=cmean; v[i].w-=cmean;
      cvs += v[i].x*v[i].x+v[i].y*v[i].y+v[i].z*v[i].z+v[i].w*v[i].w;
    }
    cvs += __shfl_xor(cvs,1); cvs += __shfl_xor(cvs,2); cvs += __shfl_xor(cvs,4);
    float crstd = rsqrtf(cvs*(1.0f/128.0f) + 1e-5f);
    if (s8 == 0) stats[(size_t)g*64 + ttk] = make_float2(cmean, crstd);
    const float* gp = lcg + s8*16; const float* bp = lcb + s8*16;
    ushort* hrow = &sh_h[ttk*HSTRB + s8*16];
    #pragma unroll
    for (int i = 0; i < 2; i++){
      float4 ga = *(const float4*)(gp + i*8),  gb = *(const float4*)(gp + i*8 + 4);
      float4 ba = *(const float4*)(bp + i*8),  bb = *(const float4*)(bp + i*8 + 4);
      float4 va = v[i*2], vb2 = v[i*2+1];
      int4 o;
      o.x = (int)pk2(va.x*crstd*ga.x+ba.x,  va.y*crstd*ga.y+ba.y);
      o.y = (int)pk2(va.z*crstd*ga.z+ba.z,  va.w*crstd*ga.w+ba.w);
      o.z = (int)pk2(vb2.x*crstd*gb.x+bb.x, vb2.y*crstd*gb.y+bb.y);
      o.w = (int)pk2(vb2.z*crstd*gb.z+bb.z, vb2.w*crstd*gb.w+bb.w);
      *(int4*)&hrow[i*8] = o;
    }
  }
  __syncthreads();
  // ---- D1 (tid<256): col raw q,k -> [b][l][h][n] ----
  if (tid < 256){
    int h = tid>>6, n = tid&63;
    float qv = cqb[h], kv = ckb[h];
    const int4* hp = (const int4*)&sh_h[n*HSTRB];
    const float4* qwp = (const float4*)&sh_w4[1024 + h*128];
    const float4* kwp = (const float4*)&sh_w4[1536 + h*128];
    #pragma unroll 4
    for (int j=0;j<16;j++){
      int4 h8 = hp[j];
      float4 qa = qwp[2*j], qb4 = qwp[2*j+1];
      float4 ka = kwp[2*j], kb4 = kwp[2*j+1];
      float h0=bflo((u32)h8.x), h1=bfhi((u32)h8.x);
      float h2=bflo((u32)h8.y), h3=bfhi((u32)h8.y);
      float h4=bflo((u32)h8.z), h5=bfhi((u32)h8.z);
      float h6=bflo((u32)h8.w), h7=bfhi((u32)h8.w);
      qv += h0*qa.x+h1*qa.y+h2*qa.z+h3*qa.w + h4*qb4.x+h5*qb4.y+h6*qb4.z+h7*qb4.w;
      kv += h0*ka.x+h1*ka.y+h2*ka.z+h3*ka.w + h4*kb4.x+h5*kb4.y+h6*kb4.z+h7*kb4.w;
    }
    qv = qv > 0.f ? qv + 1.f : __expf(qv);
    kv = kv > 0.f ? kv + 1.f : __expf(kv);
    size_t o = (size_t)g*256 + tid;
    qout[o] = qv; kout[o] = kv;
  }
}

// ---------------- col: streaming reduce S1[d]=Σk·r·y, A=Σk, B=Σk·r·m, Q=Σq ----
__global__ __launch_bounds__(256) void k_col_s1(
    const float* __restrict__ y, const float2* __restrict__ stats,
    const float* __restrict__ qin, const float* __restrict__ kin,
    float* __restrict__ s1p, float* __restrict__ Ab, float* __restrict__ Bb,
    float* __restrict__ Qb)
{
  int gg = blockIdx.x;                   // ((b*64+n)*8+s)
  int s = gg & 7, n = (gg>>3) & 63, b = gg>>9;
  int tid = threadIdx.x;
  int li = tid>>7, d = tid&127;
  const float* kp = kin + (size_t)b*262144 + n;   // [b][l][h][n]
  const float* qp = qin + (size_t)b*262144 + n;
  float a0=0.f,a1=0.f,a2=0.f,a3=0.f;
  float A0=0.f,A1=0.f,A2=0.f,A3=0.f;
  float B0=0.f,B1=0.f,B2=0.f,B3=0.f;
  float Q0=0.f,Q1=0.f,Q2=0.f,Q3=0.f;
  for (int j=0;j<64;j++){
    int l = s*128 + 2*j + li;
    size_t t = ((size_t)(b*1024+l)*64+n);
    float2 st = stats[t];
    float w = st.y * y[t*128 + d];
    float rm = st.y*st.x;
    const float* kl = kp + (size_t)l*256;
    const float* ql = qp + (size_t)l*256;
    float k0 = kl[0], k1 = kl[64], k2 = kl[128], k3 = kl[192];
    a0 += k0*w; a1 += k1*w; a2 += k2*w; a3 += k3*w;
    A0 += k0; A1 += k1; A2 += k2; A3 += k3;
    B0 += k0*rm; B1 += k1*rm; B2 += k2*rm; B3 += k3*rm;
    Q0 += ql[0]; Q1 += ql[64]; Q2 += ql[128]; Q3 += ql[192];
  }
  __shared__ float shr[512];
  __shared__ float sAB[12];
  if (li == 1){
    shr[0*128+d]=a0; shr[1*128+d]=a1; shr[2*128+d]=a2; shr[3*128+d]=a3;
    if (d==0){ sAB[0]=A0; sAB[1]=A1; sAB[2]=A2; sAB[3]=A3;
               sAB[4]=B0; sAB[5]=B1; sAB[6]=B2; sAB[7]=B3;
               sAB[8]=Q0; sAB[9]=Q1; sAB[10]=Q2; sAB[11]=Q3; }
  }
  __syncthreads();
  if (li == 0){
    float* out = s1p + (size_t)gg*512;
    out[0*128+d] = a0 + shr[0*128+d];
    out[1*128+d] = a1 + shr[1*128+d];
    out[2*128+d] = a2 + shr[2*128+d];
    out[3*128+d] = a3 + shr[3*128+d];
    if (d==0){
      Ab[gg*4+0]=A0+sAB[0]; Ab[gg*4+1]=A1+sAB[1];
      Ab[gg*4+2]=A2+sAB[2]; Ab[gg*4+3]=A3+sAB[3];
      Bb[gg*4+0]=B0+sAB[4]; Bb[gg*4+1]=B1+sAB[5];
      Bb[gg*4+2]=B2+sAB[6]; Bb[gg*4+3]=B3+sAB[7];
      Qb[gg*4+0]=Q0+sAB[8]; Qb[gg*4+1]=Q1+sAB[9];
      Qb[gg*4+2]=Q2+sAB[10]; Qb[gg*4+3]=Q3+sAB[11];
    }
  }
}

// ---------------- col: reduce S1/A/B/Q -> hk -> ktv -> P ----------------
__global__ __launch_bounds__(256) void k_col_ktvP(
    const float* __restrict__ s1p,
    const float* __restrict__ Ab, const float* __restrict__ Bb,
    const float* __restrict__ Qb,
    const float* __restrict__ vw, const float* __restrict__ vb,
    const float* __restrict__ ow,
    const float* __restrict__ lcg, const float* __restrict__ lcb,
    float* __restrict__ Pout)
{
  int gg = blockIdx.x;   // b*64+n
  __shared__ float sh_hk[512];
  __shared__ float sh_ktv[128];
  __shared__ float sh_A[4], sh_B[4], sh_qs[4];
  int tid = threadIdx.x;
  #pragma unroll
  for (int r = 0; r < 2; r++){
    int idx = tid + r*256;
    float acc = 0.f;
    #pragma unroll
    for (int s = 0; s < 8; s++) acc += s1p[((size_t)gg*8 + s)*512 + idx];
    sh_hk[idx] = acc;
  }
  if (tid < 4){
    float a=0.f, bb=0.f, q=0.f;
    #pragma unroll
    for (int s = 0; s < 8; s++){
      a += Ab[(gg*8+s)*4+tid]; bb += Bb[(gg*8+s)*4+tid]; q += Qb[(gg*8+s)*4+tid];
    }
    sh_A[tid]=a; sh_B[tid]=bb; sh_qs[tid] = 1024.f/q;
  }
  __syncthreads();
  #pragma unroll
  for (int r = 0; r < 2; r++){
    int idx = tid + r*256;
    int h = idx>>7, d = idx&127;
    sh_hk[idx] = lcg[d]*((sh_hk[idx]-sh_B[h])/sh_A[h]) + lcb[d];
  }
  __syncthreads();
  if (tid < 128){
    float acc = vb[tid];
    const float* vr = vw + (size_t)tid*128;
    const float* hp2 = sh_hk + (tid>>5)*128;
    #pragma unroll 4
    for (int d = 0; d < 128; d++) acc += vr[d]*hp2[d];
    sh_ktv[tid] = acc;
  }
  __syncthreads();
  #pragma unroll
  for (int r = 0; r < 2; r++){
    int idx = tid + r*256;
    int hh = idx >> 7, e = idx & 127;
    float acc = 0.f;
    const float* orow = ow + (size_t)e*128 + hh*32;
    #pragma unroll 4
    for (int j = 0; j < 32; j++) acc += orow[j]*sh_ktv[hh*32+j];
    Pout[(size_t)gg*512 + hh*128 + e] = acc * sh_qs[hh];
  }
}

// ---------------- fused col-out + FFN (bf16 MFMA, pipelined gload_lds) ----------------
__global__ __launch_bounds__(512, 4) void k_ffn(
    float* __restrict__ y,
    const float* __restrict__ qbuf, const float* __restrict__ Pb,
    const float* __restrict__ cob,
    const float* __restrict__ gam, const float* __restrict__ bet,
    const ushort* __restrict__ w1b, const float* __restrict__ b1,
    const ushort* __restrict__ w2b, const float* __restrict__ b2)
{
  __shared__ __align__(16) ushort pool[29952];  // 59904 B
  ushort* sW1 = pool;            // w1 chunk, 64 x 128
  ushort* sW2 = pool + 8192;     // w2 chunk, 128 x 64
  ushort* sH  = pool + 16384;    // 64 x 136
  ushort* sHf = pool + 25088;    // 64 x 72
  float*  sF  = (float*)pool;    // epilogue overlay, 64 x 132
  int tid = threadIdx.x;
  int g = blockIdx.x;
  size_t tb = (size_t)g*64;

  int wid = tid>>6, ln = tid&63;
  int lr = ln&15, gq = ln>>4;
  int wt = wid>>1, we = wid&1;
  int t0 = wt*16;

  #pragma unroll
  for (int i = 0; i < 2; i++){
    int row = wid*8 + i*4 + (ln>>4);
    gl_lds16(w1b + (size_t)row*128 + (((ln&15) ^ (row&7))<<3),
             &sW1[(wid*8 + i*4)*128]);
  }
  #pragma unroll
  for (int i = 0; i < 2; i++){
    int row = wid*16 + i*8 + (ln>>3);
    gl_lds16(w2b + (size_t)row*512 + (((ln&7) ^ (row&7))<<3),
             &sW2[(wid*16 + i*8)*64]);
  }

  int ttk = tid>>3, s8 = tid&7;
  float* yr = y + (tb+ttk)*128 + s8*16;
  float4 v[4];
  float fmean;
  {
    #pragma unroll
    for (int i = 0; i < 4; i++) v[i] = *(const float4*)(yr + i*4);
    const float* qp = qbuf + (size_t)g*256 + ttk;   // [b][l][h][n]
    float q0 = qp[0], q1 = qp[64], q2 = qp[128], q3 = qp[192];
    const float* pr = Pb + ((size_t)((g>>10)*64 + ttk))*512 + s8*16;
    #pragma unroll
    for (int i = 0; i < 4; i++){
      float4 p0 = *(const float4*)(pr + i*4);
      float4 p1 = *(const float4*)(pr + 128 + i*4);
      float4 p2 = *(const float4*)(pr + 256 + i*4);
      float4 p3 = *(const float4*)(pr + 384 + i*4);
      float4 c4 = *(const float4*)&cob[s8*16 + i*4];
      v[i].x += c4.x + q0*p0.x+q1*p1.x+q2*p2.x+q3*p3.x;
      v[i].y += c4.y + q0*p0.y+q1*p1.y+q2*p2.y+q3*p3.y;
      v[i].z += c4.z + q0*p0.z+q1*p1.z+q2*p2.z+q3*p3.z;
      v[i].w += c4.w + q0*p0.w+q1*p1.w+q2*p2.w+q3*p3.w;
    }
    float sum = 0.f;
    #pragma unroll
    for (int i = 0; i < 4; i++) sum += v[i].x+v[i].y+v[i].z+v[i].w;
    sum += __shfl_xor(sum,1); sum += __shfl_xor(sum,2); sum += __shfl_xor(sum,4);
    fmean = sum*(1.0f/128.0f);
    float vs = 0.f;
    #pragma unroll
    for (int i = 0; i < 4; i++){
      v[i].x-=fmean; v[i].y-=fmean; v[i].z-=fmean; v[i].w-=fmean;
      vs += v[i].x*v[i].x+v[i].y*v[i].y+v[i].z*v[i].z+v[i].w*v[i].w;
    }
    vs += __shfl_xor(vs,1); vs += __shfl_xor(vs,2); vs += __shfl_xor(vs,4);
    float rstd = rsqrtf(vs*(1.0f/128.0f) + 1e-5f);
    const float* gp = gam + s8*16; const float* bp = bet + s8*16;
    #pragma unroll
    for (int i = 0; i < 2; i++){
      float4 ga = *(const float4*)(gp + i*8),     gb = *(const float4*)(gp + i*8 + 4);
      float4 ba = *(const float4*)(bp + i*8),     bb = *(const float4*)(bp + i*8 + 4);
      float4 va = v[i*2], vb2 = v[i*2+1];
      int4 o;
      o.x = (int)pk2(va.x*rstd*ga.x+ba.x,  va.y*rstd*ga.y+ba.y);
      o.y = (int)pk2(va.z*rstd*ga.z+ba.z,  va.w*rstd*ga.w+ba.w);
      o.z = (int)pk2(vb2.x*rstd*gb.x+bb.x, vb2.y*rstd*gb.y+bb.y);
      o.w = (int)pk2(vb2.z*rstd*gb.z+bb.z, vb2.w*rstd*gb.w+bb.w);
      *(int4*)&sH[ttk*136 + s8*16 + i*8] = o;
    }
  }
  __syncthreads();

  f32x4 acc2[4] = {};

  for (int c = 0; c < 8; c++){
    f32x4 acc1[2] = {};
    #pragma unroll
    for (int ks = 0; ks < 4; ks++){
      bf16x8 bfv = *(const bf16x8*)&sH[(t0+lr)*136 + ks*32 + gq*8];
      #pragma unroll
      for (int i = 0; i < 2; i++){
        int er = we*32 + i*16 + lr;
        bf16x8 afv = *(const bf16x8*)&sW1[er*128 + ((((ks<<2)|gq) ^ (lr&7))<<3)];
        acc1[i] = __builtin_amdgcn_mfma_f32_16x16x32_bf16(afv, bfv, acc1[i], 0, 0, 0);
      }
    }
    #pragma unroll
    for (int i = 0; i < 2; i++){
      float4 bb = *(const float4*)&b1[c*64 + we*32 + i*16 + gq*4];
      ushort4 pk;
      pk.x = bfr(fast_gelu(acc1[i][0] + bb.x));
      pk.y = bfr(fast_gelu(acc1[i][1] + bb.y));
      pk.z = bfr(fast_gelu(acc1[i][2] + bb.z));
      pk.w = bfr(fast_gelu(acc1[i][3] + bb.w));
      *(ushort4*)&sHf[(t0+lr)*72 + we*32 + i*16 + gq*4] = pk;
    }
    __syncthreads();
    if (c < 7){
      #pragma unroll
      for (int i = 0; i < 2; i++){
        int row = wid*8 + i*4 + (ln>>4);
        gl_lds16(w1b + (size_t)(c+1)*8192 + (size_t)row*128 + (((ln&15) ^ (row&7))<<3),
                 &sW1[(wid*8 + i*4)*128]);
      }
    }
    #pragma unroll
    for (int ks = 0; ks < 2; ks++){
      bf16x8 bfv = *(const bf16x8*)&sHf[(t0+lr)*72 + ks*32 + gq*8];
      #pragma unroll
      for (int j = 0; j < 4; j++){
        int dr = we*64 + j*16 + lr;
        bf16x8 afv = *(const bf16x8*)&sW2[dr*64 + ((((ks<<2)|gq) ^ (lr&7))<<3)];
        acc2[j] = __builtin_amdgcn_mfma_f32_16x16x32_bf16(afv, bfv, acc2[j], 0, 0, 0);
      }
    }
    __syncthreads();
    if (c < 7){
      #pragma unroll
      for (int i = 0; i < 2; i++){
        int row = wid*16 + i*8 + (ln>>3);
        gl_lds16(w2b + (size_t)row*512 + (c+1)*64 + (((ln&7) ^ (row&7))<<3),
                 &sW2[(wid*16 + i*8)*64]);
      }
    }
  }

  #pragma unroll
  for (int j = 0; j < 4; j++){
    float4 fo; fo.x=acc2[j][0]; fo.y=acc2[j][1]; fo.z=acc2[j][2]; fo.w=acc2[j][3];
    *(float4*)&sF[(t0+lr)*132 + we*64 + j*16 + gq*4] = fo;
  }
  __syncthreads();
  #pragma unroll
  for (int i = 0; i < 4; i++){
    float4 f = *(const float4*)&sF[ttk*132 + s8*16 + i*4];
    float4 b4 = *(const float4*)&b2[s8*16 + i*4];
    float4 o;
    o.x = v[i].x + fmean + f.x + b4.x;
    o.y = v[i].y + fmean + f.y + b4.y;
    o.z = v[i].z + fmean + f.z + b4.z;
    o.w = v[i].w + fmean + f.w + b4.w;
    *(float4*)(yr + i*4) = o;
  }
}

// ---------------- head: xb partials (4 l-slices) + reduce ----------------
__global__ __launch_bounds__(128) void k_xbp(const float* __restrict__ y,
                                             float* __restrict__ xbq){
  int gg = blockIdx.x;   // (b*64+n)*4 + s
  int s = gg & 3, n = (gg>>2) & 63, b = gg>>8;
  int d = threadIdx.x;
  float acc = 0.f;
  int l0 = s*256 + (s==0 ? 1 : 0);
  const float* p = y + (((size_t)b*1024 + l0)*64 + n)*128 + d;
  for (int l = l0; l < s*256+256; l++){ acc += *p; p += 64*128; }
  xbq[(size_t)gg*128 + d] = acc;
}
__global__ __launch_bounds__(128) void k_xbr(const float* __restrict__ xbq,
                                             float* __restrict__ xb){
  int gg = blockIdx.x;   // b*64+n
  int d = threadIdx.x;
  const float* q = xbq + (size_t)gg*512;
  xb[(size_t)gg*128 + d] = (q[d] + q[128+d] + q[256+d] + q[384+d]) * (1.0f/1023.0f);
}

// ---------------- head: pairwise distances ----------------
__global__ __launch_bounds__(64) void k_dist(const float* __restrict__ xb,
                                             float* __restrict__ out){
  int p = blockIdx.x;           // b*2016 + pair
  int b = p >= 2016 ? 1 : 0;
  int pr = p - b*2016;
  int i0 = (int)((1.0f + sqrtf(1.0f + 8.0f*(float)pr))*0.5f);
  while (i0*(i0-1)/2 > pr) i0--;
  while ((i0+1)*i0/2 <= pr) i0++;
  int i1 = pr - i0*(i0-1)/2;
  int lane = threadIdx.x;
  const float* xa = xb + ((size_t)b*64 + i0)*128;
  const float* xc = xb + ((size_t)b*64 + i1)*128;
  float d0 = xa[lane]-xc[lane], d1 = xa[lane+64]-xc[lane+64];
  float s = d0*d0 + d1*d1;
  for (int m=32;m>=1;m>>=1) s += __shfl_xor(s, m);
  if (lane == 0) out[p] = sqrtf(s + 1e-8f);
}

extern "C" void kernel_launch(void* const* d_in, const int* in_sizes, int n_in,
                              void* d_out, int out_size, void* d_ws, size_t ws_size,
                              hipStream_t stream){
  const float* x    = (const float*)d_in[0];
  const float* rq_w = (const float*)d_in[1];  const float* rq_b = (const float*)d_in[2];
  const float* rk_w = (const float*)d_in[3];  const float* rk_b = (const float*)d_in[4];
  const float* rv_w = (const float*)d_in[5];  const float* rv_b = (const float*)d_in[6];
  const float* ro_w = (const float*)d_in[7];  const float* ro_b = (const float*)d_in[8];
  const float* cq_w = (const float*)d_in[9];  const float* cq_b = (const float*)d_in[10];
  const float* ck_w = (const float*)d_in[11]; const float* ck_b = (const float*)d_in[12];
  const float* cv_w = (const float*)d_in[13]; const float* cv_b = (const float*)d_in[14];
  const float* co_w = (const float*)d_in[15]; const float* co_b = (const float*)d_in[16];
  const float* lrg  = (const float*)d_in[17]; const float* lrb  = (const float*)d_in[18];
  const float* lcg  = (const float*)d_in[19]; const float* lcb  = (const float*)d_in[20];
  const float* lfg  = (const float*)d_in[21]; const float* lfb  = (const float*)d_in[22];
  const float* f1w  = (const float*)d_in[23]; const float* f1b  = (const float*)d_in[24];
  const float* f2w  = (const float*)d_in[25]; const float* f2b  = (const float*)d_in[26];

  float* ws = (float*)d_ws;
  float*  y   = ws;                           // 16777216
  float2* st  = (float2*)(ws + 16777216);     // 262144 floats
  float*  qb_ = ws + 17039360;                // 524288
  float*  kb_ = ws + 17563648;                // 524288
  float*  Pb  = ws + 18087936;                // 1048576
  float*  s1p = ws + 19136512;                // 524288
  float*  xb  = ws + 19661824;                // 16384
  ushort* w1b = (ushort*)(ws + 19678208);     // 262144 ushorts
  ushort* w2b = (ushort*)(ws + 19809280);     // 262144 ushorts
  float*  xbq = ws + 19940352;                // 65536
  float*  Ab  = ws + 20005888;                // 4096
  float*  Bb  = ws + 20009984;                // 4096
  float*  Qb  = ws + 20014080;                // 4096

  k_transpose<<<dim3(2048), dim3(256), 0, stream>>>(x, y);
  k_cvt<<<dim3(256), dim3(256), 0, stream>>>(f1w, w1b, 65536);
  k_cvt<<<dim3(256), dim3(256), 0, stream>>>(f2w, w2b, 65536);
  for (int l = 0; l < LCNT; l++){
    k_row<<<dim3(2048), dim3(512), 0, stream>>>(y,
        rq_w + l*512, rq_b + l*4, rk_w + l*512, rk_b + l*4,
        rv_w + (size_t)l*16384, rv_b + l*128, ro_w + (size_t)l*16384, ro_b + l*128,
        lrg + l*128, lrb + l*128,
        cq_w + l*512, cq_b + l*4, ck_w + l*512, ck_b + l*4,
        lcg + l*128, lcb + l*128,
        st, qb_, kb_);
    k_col_s1<<<dim3(1024), dim3(256), 0, stream>>>(y, st, qb_, kb_, s1p, Ab, Bb, Qb);
    k_col_ktvP<<<dim3(128), dim3(256), 0, stream>>>(s1p, Ab, Bb, Qb,
        cv_w + (size_t)l*16384, cv_b + l*128, co_w + (size_t)l*16384,
        lcg + l*128, lcb + l*128, Pb);
    k_ffn<<<dim3(2048), dim3(512), 0, stream>>>(y, qb_, Pb, co_b + l*128,
        lfg + l*128, lfb + l*128,
        w1b + (size_t)l*65536, f1b + l*512, w2b + (size_t)l*65536, f2b + l*128);
  }
  k_xbp<<<dim3(512), dim3(128), 0, stream>>>(y, xbq);
  k_xbr<<<dim3(128), dim3(128), 0, stream>>>(xbq, xb);
  k_dist<<<dim3(4032), dim3(64), 0, stream>>>(xb, (float*)d_out);
}